// Round 8
// baseline (233.567 us; speedup 1.0000x reference)
//
#include <hip/hip_runtime.h>
#include <hip/hip_bf16.h>

#define N_ATOMS 8192
#define N_PAIR  131072
#define F       128
#define N_HEAD  8
#define FH      16
#define N_DEG   3
#define M_TOT   15
#define K_RBF   32
#define H_FILT  64
#define FILT_OUT 768
#define NDH     24   // N_DEG * N_HEAD
#define ATB     4    // atoms per aggr block

typedef __attribute__((ext_vector_type(8))) unsigned short u16x8;

__device__ __forceinline__ float bf2f(unsigned short u) {
    return __uint_as_float(((unsigned)u) << 16);
}
__device__ __forceinline__ unsigned short f2bfbits(float f) {
    __hip_bfloat16 b = __float2bfloat16(f);
    return *reinterpret_cast<unsigned short*>(&b);
}

// ---------------- K0: segment starts (idx_i is sorted) ----------------
__global__ void k_seg(const int* __restrict__ idx_i, int* __restrict__ row_start) {
    int p = blockIdx.x * 256 + threadIdx.x;
    if (p >= N_PAIR) return;
    int ii = idx_i[p];
    int prev = (p == 0) ? -1 : idx_i[p - 1];
    for (int a = prev + 1; a <= ii; ++a) row_start[a] = p;
    if (p == N_PAIR - 1) {
        for (int a = ii + 1; a <= N_ATOMS; ++a) row_start[a] = N_PAIR;
    }
}

// ---------------- zero counters (graph-replay safe) ----------------
__global__ void k_zero(int* __restrict__ counts, int* __restrict__ cnt2) {
    int t = blockIdx.x * 256 + threadIdx.x;
    if (t < N_ATOMS) { counts[t] = 0; cnt2[t] = 0; }
}

// ---------------- histogram of idx_j ----------------
__global__ void k_hist(const int* __restrict__ idx_j, int* __restrict__ counts) {
    int p = blockIdx.x * 256 + threadIdx.x;
    if (p < N_PAIR) atomicAdd(&counts[idx_j[p]], 1);
}

// ---------------- exclusive scan of 8192 counts (1 block) ----------------
__global__ __launch_bounds__(1024) void k_scan(const int* __restrict__ counts,
                                               int* __restrict__ offsets) {
    __shared__ int ts[1024];
    int tid = threadIdx.x;
    int base = tid * 8;
    int v[8]; int tot = 0;
    #pragma unroll
    for (int q = 0; q < 8; ++q) { v[q] = counts[base + q]; tot += v[q]; }
    ts[tid] = tot; __syncthreads();
    for (int off = 1; off < 1024; off <<= 1) {
        int t2 = (tid >= off) ? ts[tid - off] : 0;
        __syncthreads();
        ts[tid] += t2;
        __syncthreads();
    }
    int excl = ts[tid] - tot;
    #pragma unroll
    for (int q = 0; q < 8; ++q) { offsets[base + q] = excl; excl += v[q]; }
    if (tid == 1023) offsets[N_ATOMS] = ts[1023];
}

// ---------------- placement: sorted pair ids per j-bucket + rank ----------------
__global__ void k_place(const int* __restrict__ idx_j, const int* __restrict__ offsets,
                        int* __restrict__ cnt2, int* __restrict__ sorted,
                        int* __restrict__ rank) {
    int p = blockIdx.x * 256 + threadIdx.x;
    if (p < N_PAIR) {
        int j = idx_j[p];
        int pos = offsets[j] + atomicAdd(&cnt2[j], 1);
        sorted[pos] = p;
        rank[p] = pos;
    }
}

// ---------------- K_wc: combined weights ----------------
__global__ __launch_bounds__(256) void k_wc(
    const float* __restrict__ WQ, const float* __restrict__ WK,
    const float* __restrict__ avec, const float* __restrict__ W2,
    const float* __restrict__ b2,
    float* __restrict__ Wc, float* __restrict__ bc)
{
    int bx = blockIdx.x;             // 0..47
    int side = bx / NDH, dh = bx % NDH;
    int d = dh >> 3, h = dh & 7;
    int colbase = d * 256 + h * 32 + side * 16;
    const float* W = (side == 0) ? WQ : WK;
    __shared__ float w2s[64][16];
    __shared__ float ws[16][16];     // W[d][h][c][j]
    __shared__ float as[16];
    __shared__ float b2s[16];
    int tid = threadIdx.x;
    for (int e = tid; e < 64 * 16; e += 256)
        w2s[e >> 4][e & 15] = W2[(e >> 4) * FILT_OUT + colbase + (e & 15)];
    if (tid < 16 * 16) ws[tid >> 4][tid & 15] = W[((d * 8 + h) * 16) * 16 + tid];
    if (tid < 16) { as[tid] = avec[dh * 32 + side * 16 + tid]; b2s[tid] = b2[colbase + tid]; }
    __syncthreads();
    for (int o = tid; o < 64 * 16; o += 256) {
        int k = o >> 4, j = o & 15;
        float s = 0.f;
        #pragma unroll
        for (int c = 0; c < 16; ++c) s += w2s[k][c] * as[c] * ws[c][j];
        Wc[((size_t)bx * 64 + k) * 16 + j] = s;
    }
    if (tid < 16) {
        float s = 0.f;
        #pragma unroll
        for (int c = 0; c < 16; ++c) s += b2s[c] * as[c] * ws[c][tid];
        bc[bx * 16 + tid] = s;
    }
}

// ---------------- K_gfused: x -> Gq/Gk/bq/bk directly ----------------
__global__ __launch_bounds__(256) void k_gfused(
    const float* __restrict__ x, const float* __restrict__ Wc,
    const float* __restrict__ bc,
    __hip_bfloat16* __restrict__ Gq, __hip_bfloat16* __restrict__ Gk,
    float* __restrict__ bq, float* __restrict__ bk)
{
    int bx = blockIdx.x;             // 128 blocks of 64 atoms
    int by = blockIdx.y;             // 0..47: side, dh
    int side = by / NDH, dh = by % NDH;
    int h = dh & 7;
    int n0 = bx * 64;
    __shared__ float xh[64][17];     // padded: conflict-free per-at reads
    __shared__ float bcs[16];
    int tid = threadIdx.x;
    for (int e = tid; e < 64 * 16; e += 256)
        xh[e >> 4][e & 15] = x[(size_t)(n0 + (e >> 4)) * F + h * 16 + (e & 15)];
    if (tid < 16) bcs[tid] = bc[by * 16 + tid];
    int k = tid & 63, wv = tid >> 6;
    float wcr[16];
    const float* wp = Wc + ((size_t)by * 64 + k) * 16;
    #pragma unroll
    for (int j = 0; j < 16; ++j) wcr[j] = wp[j];
    __syncthreads();
    __hip_bfloat16* G = (side == 0) ? Gq : Gk;
    #pragma unroll 4
    for (int it = 0; it < 16; ++it) {
        int at = wv * 16 + it;
        float acc = 0.f;
        #pragma unroll
        for (int j = 0; j < 16; ++j) acc += wcr[j] * xh[at][j];  // broadcast reads
        G[(size_t)(n0 + at) * 1536 + dh * 64 + k] = __float2bfloat16(acc);
    }
    if (tid < 64) {
        float* B = (side == 0) ? bq : bk;
        float s = 0.f;
        #pragma unroll
        for (int j = 0; j < 16; ++j) s += bcs[j] * xh[tid][j];
        B[(n0 + tid) * NDH + dh] = s;
    }
}

// ---------------- K2a: h1[p,64] = silu(rbf @ W1 + b1), bf16 ----------------
__global__ __launch_bounds__(256) void k_h1(
    const float* __restrict__ rbf, const float* __restrict__ W1,
    const float* __restrict__ b1, unsigned short* __restrict__ h1)
{
    __shared__ float w1s[K_RBF][H_FILT]; // 8 KB
    __shared__ float b1s[H_FILT];
    __shared__ float rbfs[64][33];       // padded
    int tid = threadIdx.x;
    int p0 = blockIdx.x * 64;
    for (int e = tid; e < K_RBF * H_FILT; e += 256) w1s[e >> 6][e & 63] = W1[e];
    if (tid < H_FILT) b1s[tid] = b1[tid];
    for (int e = tid; e < 64 * K_RBF; e += 256)
        rbfs[e >> 5][e & 31] = rbf[(size_t)p0 * K_RBF + e];
    __syncthreads();
    int pp = tid >> 2;
    int kbase = (tid & 3) * 16;
    float acc[16];
    #pragma unroll
    for (int q = 0; q < 16; ++q) acc[q] = b1s[kbase + q];
    for (int c = 0; c < K_RBF; ++c) {
        float r = rbfs[pp][c];
        #pragma unroll
        for (int q = 0; q < 16; ++q) acc[q] += r * w1s[c][kbase + q];
    }
    u16x8 o0, o1;
    #pragma unroll
    for (int q = 0; q < 8; ++q) {
        float s0 = acc[q];     o0[q] = f2bfbits(s0 / (1.f + __expf(-s0)));
        float s1 = acc[q + 8]; o1[q] = f2bfbits(s1 / (1.f + __expf(-s1)));
    }
    unsigned short* hp = h1 + (size_t)(p0 + pp) * 64 + kbase;
    *reinterpret_cast<u16x8*>(hp) = o0;
    *reinterpret_cast<u16x8*>(hp + 8) = o1;
}

// ---------------- K2c: K-side alpha, software-pipelined, sequential bf16 output ----------------
__global__ __launch_bounds__(256) void k_alphak(
    const int* __restrict__ sorted, const int* __restrict__ idx_j,
    const unsigned short* __restrict__ h1,
    const __hip_bfloat16* __restrict__ Gk, const float* __restrict__ bk,
    unsigned short* __restrict__ alphaKs)
{
    __shared__ unsigned short h1s[64][64]; // 8 KB
    __shared__ int ps[64];
    __shared__ int js[64];
    int tid = threadIdx.x;
    int c0 = blockIdx.x * 64;
    if (tid < 64) {
        int pid = sorted[c0 + tid];
        ps[tid] = pid;
        js[tid] = idx_j[pid];
    }
    __syncthreads();
    for (int e = tid; e < 64 * 8; e += 256) {
        int slot = e >> 3, seg = e & 7;
        *reinterpret_cast<u16x8*>(&h1s[slot][seg * 8]) =
            *reinterpret_cast<const u16x8*>(h1 + (size_t)ps[slot] * 64 + seg * 8);
    }
    __syncthreads();

    const unsigned short* GkU = reinterpret_cast<const unsigned short*>(Gk);
    unsigned sA, dA, sB, dB;
    const unsigned short* gA; const unsigned short* gB;
    float bkA, bkB;
    u16x8 vA[8], vB[8];

#define AK_ADDRLOAD(S, D, G, BK, V, T)                                   \
    { unsigned task = (T) * 256u + (unsigned)tid;                        \
      S = task / 24u; D = task - S * 24u;                                \
      int j_ = js[S];                                                    \
      G = GkU + (size_t)j_ * 1536 + D * 64;                              \
      BK = bk[j_ * NDH + D];                                             \
      _Pragma("unroll")                                                  \
      for (int v = 0; v < 8; ++v) V[v] = *reinterpret_cast<const u16x8*>(G + v * 8); }

#define AK_COMP(S, BK, V, T)                                             \
    { float a0 = 0.f, a1 = 0.f, a2 = 0.f, a3 = 0.f;                      \
      _Pragma("unroll")                                                  \
      for (int v = 0; v < 8; ++v) {                                      \
        u16x8 hv = *reinterpret_cast<const u16x8*>(&h1s[S][v * 8]);      \
        a0 += bf2f(V[v][0]) * bf2f(hv[0]);                               \
        a1 += bf2f(V[v][1]) * bf2f(hv[1]);                               \
        a2 += bf2f(V[v][2]) * bf2f(hv[2]);                               \
        a3 += bf2f(V[v][3]) * bf2f(hv[3]);                               \
        a0 += bf2f(V[v][4]) * bf2f(hv[4]);                               \
        a1 += bf2f(V[v][5]) * bf2f(hv[5]);                               \
        a2 += bf2f(V[v][6]) * bf2f(hv[6]);                               \
        a3 += bf2f(V[v][7]) * bf2f(hv[7]);                               \
      }                                                                  \
      alphaKs[(size_t)c0 * 24 + (T) * 256 + tid] =                       \
          f2bfbits(BK + (a0 + a1) + (a2 + a3)); }

    AK_ADDRLOAD(sA, dA, gA, bkA, vA, 0);
    AK_ADDRLOAD(sB, dB, gB, bkB, vB, 1); AK_COMP(sA, bkA, vA, 0);
    AK_ADDRLOAD(sA, dA, gA, bkA, vA, 2); AK_COMP(sB, bkB, vB, 1);
    AK_ADDRLOAD(sB, dB, gB, bkB, vB, 3); AK_COMP(sA, bkA, vA, 2);
    AK_ADDRLOAD(sA, dA, gA, bkA, vA, 4); AK_COMP(sB, bkB, vB, 3);
    AK_ADDRLOAD(sB, dB, gB, bkB, vB, 5); AK_COMP(sA, bkA, vA, 4);
    AK_COMP(sB, bkB, vB, 5);
#undef AK_ADDRLOAD
#undef AK_COMP
}

// ---------------- K2d: full alpha in p-order: (dotQ + bq + alphaKs[rank]) * phi*mask/4 ----------------
__global__ __launch_bounds__(256) void k_alphaA(
    const int* __restrict__ idx_i, const int* __restrict__ rank,
    const float* __restrict__ phi, const float* __restrict__ mask,
    const unsigned short* __restrict__ h1,
    const __hip_bfloat16* __restrict__ Gq, const float* __restrict__ bq,
    const unsigned short* __restrict__ alphaKs,
    float* __restrict__ alphaF)
{
    __shared__ unsigned short h1s[64][64]; // 8 KB
    __shared__ int is[64];
    __shared__ int rks[64];
    __shared__ float pms[64];
    int tid = threadIdx.x;
    int p0 = blockIdx.x * 64;
    if (tid < 64) {
        int p = p0 + tid;
        is[tid] = idx_i[p];
        rks[tid] = rank[p];
        pms[tid] = phi[p] * mask[p] * 0.25f;
    }
    __syncthreads();
    for (int e = tid; e < 64 * 8; e += 256) {
        int slot = e >> 3, seg = e & 7;
        *reinterpret_cast<u16x8*>(&h1s[slot][seg * 8]) =
            *reinterpret_cast<const u16x8*>(h1 + (size_t)(p0 + slot) * 64 + seg * 8);
    }
    __syncthreads();

    const unsigned short* GqU = reinterpret_cast<const unsigned short*>(Gq);
    unsigned sA, dA, sB, dB;
    float baseA, baseB, pmA, pmB;
    u16x8 vA[8], vB[8];

#define QA_ADDRLOAD(S, D, BASE, PM, V, T)                                \
    { unsigned task = (T) * 256u + (unsigned)tid;                        \
      S = task / 24u; D = task - S * 24u;                                \
      int i_ = is[S];                                                    \
      const unsigned short* G = GqU + (size_t)i_ * 1536 + D * 64;        \
      BASE = bq[i_ * NDH + D] + bf2f(alphaKs[(size_t)rks[S] * 24 + D]);  \
      PM = pms[S];                                                       \
      _Pragma("unroll")                                                  \
      for (int v = 0; v < 8; ++v) V[v] = *reinterpret_cast<const u16x8*>(G + v * 8); }

#define QA_COMP(S, BASE, PM, V, T)                                       \
    { float a0 = 0.f, a1 = 0.f, a2 = 0.f, a3 = 0.f;                      \
      _Pragma("unroll")                                                  \
      for (int v = 0; v < 8; ++v) {                                      \
        u16x8 hv = *reinterpret_cast<const u16x8*>(&h1s[S][v * 8]);      \
        a0 += bf2f(V[v][0]) * bf2f(hv[0]);                               \
        a1 += bf2f(V[v][1]) * bf2f(hv[1]);                               \
        a2 += bf2f(V[v][2]) * bf2f(hv[2]);                               \
        a3 += bf2f(V[v][3]) * bf2f(hv[3]);                               \
        a0 += bf2f(V[v][4]) * bf2f(hv[4]);                               \
        a1 += bf2f(V[v][5]) * bf2f(hv[5]);                               \
        a2 += bf2f(V[v][6]) * bf2f(hv[6]);                               \
        a3 += bf2f(V[v][7]) * bf2f(hv[7]);                               \
      }                                                                  \
      alphaF[(size_t)p0 * 24 + (T) * 256 + tid] =                        \
          (BASE + (a0 + a1) + (a2 + a3)) * PM; }

    QA_ADDRLOAD(sA, dA, baseA, pmA, vA, 0);
    QA_ADDRLOAD(sB, dB, baseB, pmB, vB, 1); QA_COMP(sA, baseA, pmA, vA, 0);
    QA_ADDRLOAD(sA, dA, baseA, pmA, vA, 2); QA_COMP(sB, baseB, pmB, vB, 1);
    QA_ADDRLOAD(sB, dB, baseB, pmB, vB, 3); QA_COMP(sA, baseA, pmA, vA, 2);
    QA_ADDRLOAD(sA, dA, baseA, pmA, vA, 4); QA_COMP(sB, baseB, pmB, vB, 3);
    QA_ADDRLOAD(sB, dB, baseB, pmB, vB, 5); QA_COMP(sA, baseA, pmA, vA, 4);
    QA_COMP(sB, baseB, pmB, vB, 5);
#undef QA_ADDRLOAD
#undef QA_COMP
}

// ---------------- K3: multi-atom segment-sum with register accumulators ----------------
__global__ __launch_bounds__(256) void k_aggr4(
    const float* __restrict__ x, const float* __restrict__ sph,
    const float* __restrict__ mask,
    const int* __restrict__ idx_i, const int* __restrict__ idx_j,
    const float* __restrict__ alphaF,
    const int* __restrict__ row_start, float* __restrict__ out)
{
    int a0 = blockIdx.x * ATB;
    int tid = threadIdx.x;
    int f = tid & 127, grp = tid >> 7, h = f >> 4;

    __shared__ float xls[32][128];   // 16 KB (x rows * mask)
    __shared__ float als[32][24];    // 3 KB
    __shared__ float sls[32][15];    // 1.9 KB
    __shared__ int   iis[32];
    __shared__ int   jjs[32];
    __shared__ float xms[32];
    __shared__ int   rs[ATB + 1];

    if (tid <= ATB) rs[tid] = row_start[a0 + tid];
    __syncthreads();
    int pstart = rs[0], pend = rs[ATB];

    float acc[8];
    #pragma unroll
    for (int m = 0; m < 8; ++m) acc[m] = 0.f;
    int cur = -1;

    for (int pc = pstart; pc < pend; pc += 32) {
        int nb = min(32, pend - pc);
        __syncthreads();
        if (tid < nb) {
            int p = pc + tid;
            iis[tid] = idx_i[p];
            jjs[tid] = idx_j[p];
            xms[tid] = mask[p];
        }
        for (int e = tid; e < nb * 24; e += 256)
            als[e / 24][e % 24] = alphaF[(size_t)pc * 24 + e];
        for (int e = tid; e < nb * 15; e += 256)
            sls[e / 15][e % 15] = sph[(size_t)pc * 15 + e];
        __syncthreads();
        for (int e = tid; e < nb * 32; e += 256) {
            int q = e >> 5, c4 = e & 31;
            float4 v = *reinterpret_cast<const float4*>(x + (size_t)jjs[q] * F + c4 * 4);
            float m_ = xms[q];
            v.x *= m_; v.y *= m_; v.z *= m_; v.w *= m_;
            *reinterpret_cast<float4*>(&xls[q][c4 * 4]) = v;
        }
        __syncthreads();
        for (int q = 0; q < nb; ++q) {
            int ia = iis[q];
            if (ia != cur) {                 // uniform across block
                if (cur >= 0) {
                    size_t ob = (size_t)cur * (M_TOT * F) + f;
                    if (grp == 0) {
                        #pragma unroll
                        for (int m = 0; m < 8; ++m) out[ob + m * 128] = acc[m];
                    } else {
                        #pragma unroll
                        for (int m = 0; m < 7; ++m) out[ob + (8 + m) * 128] = acc[m];
                    }
                }
                cur = ia;
                #pragma unroll
                for (int m = 0; m < 8; ++m) acc[m] = 0.f;
            }
            float xv = xls[q][f];
            if (grp == 0) {
                float t0 = als[q][h] * xv;
                float t1 = als[q][8 + h] * xv;
                acc[0] += t0 * sls[q][0];
                acc[1] += t0 * sls[q][1];
                acc[2] += t0 * sls[q][2];
                #pragma unroll
                for (int m = 3; m < 8; ++m) acc[m] += t1 * sls[q][m];
            } else {
                float t2 = als[q][16 + h] * xv;
                #pragma unroll
                for (int m = 0; m < 7; ++m) acc[m] += t2 * sls[q][8 + m];
            }
        }
    }
    if (cur >= 0) {
        size_t ob = (size_t)cur * (M_TOT * F) + f;
        if (grp == 0) {
            #pragma unroll
            for (int m = 0; m < 8; ++m) out[ob + m * 128] = acc[m];
        } else {
            #pragma unroll
            for (int m = 0; m < 7; ++m) out[ob + (8 + m) * 128] = acc[m];
        }
    }
    // zero-fill atoms with no pairs
    for (int a = 0; a < ATB; ++a) {
        if (rs[a] == rs[a + 1]) {
            size_t ob = (size_t)(a0 + a) * (M_TOT * F) + f;
            if (grp == 0) {
                #pragma unroll
                for (int m = 0; m < 8; ++m) out[ob + m * 128] = 0.f;
            } else {
                #pragma unroll
                for (int m = 0; m < 7; ++m) out[ob + (8 + m) * 128] = 0.f;
            }
        }
    }
}

extern "C" void kernel_launch(void* const* d_in, const int* in_sizes, int n_in,
                              void* d_out, int out_size, void* d_ws, size_t ws_size,
                              hipStream_t stream) {
    const float* x     = (const float*)d_in[0];
    const float* rbf   = (const float*)d_in[1];
    const float* sph   = (const float*)d_in[2];
    const float* phi   = (const float*)d_in[3];
    const int*   idx_i = (const int*)d_in[4];
    const int*   idx_j = (const int*)d_in[5];
    const float* mask  = (const float*)d_in[6];
    const float* WQ    = (const float*)d_in[7];
    const float* WK    = (const float*)d_in[8];
    const float* av    = (const float*)d_in[9];
    const float* W1    = (const float*)d_in[10];
    const float* b1    = (const float*)d_in[11];
    const float* W2    = (const float*)d_in[12];
    const float* b2    = (const float*)d_in[13];
    float* out = (float*)d_out;
    char* ws = (char*)d_ws;

    // ws layout (bytes):
    // Gq   bf16 [0,        25165824)
    // Gk   bf16 [25165824, 50331648)  -- dead after k_alphak; alphaF f32 (12.6MB) aliases it
    // bq   f32  [50331648, 51118080)
    // bk   f32  [51118080, 51904512)
    // row_start [51904512, 51937792)   (8193 ints, padded)
    // counts    [51937792, 51970560)
    // offsets   [51970560, 52003840)   (8193 ints, padded)
    // cnt2      [52003840, 52036608)
    // sorted    [52036608, 52560896)
    // rank      [52560896, 53085184)
    // h1   bf16 [53085184, 69862400)
    // alphaKs bf16 [69862400, 76153856)
    // Wc   f32  [76153856, 76350464)
    // bc   f32  [76350464, 76356608)
    __hip_bfloat16* Gq = (__hip_bfloat16*)(ws + 0);
    __hip_bfloat16* Gk = (__hip_bfloat16*)(ws + 25165824);
    float* alphaF = (float*)(ws + 25165824);       // aliases Gk (dead after k_alphak)
    float* bq = (float*)(ws + 50331648);
    float* bk = (float*)(ws + 51118080);
    int* row_start = (int*)(ws + 51904512);
    int* counts    = (int*)(ws + 51937792);
    int* offsets   = (int*)(ws + 51970560);
    int* cnt2      = (int*)(ws + 52003840);
    int* sorted    = (int*)(ws + 52036608);
    int* rank      = (int*)(ws + 52560896);
    unsigned short* h1      = (unsigned short*)(ws + 53085184);
    unsigned short* alphaKs = (unsigned short*)(ws + 69862400);
    float* Wc = (float*)(ws + 76153856);
    float* bc = (float*)(ws + 76350464);

    k_zero<<<(N_ATOMS + 255) / 256, 256, 0, stream>>>(counts, cnt2);
    k_seg<<<(N_PAIR + 255) / 256, 256, 0, stream>>>(idx_i, row_start);
    k_hist<<<(N_PAIR + 255) / 256, 256, 0, stream>>>(idx_j, counts);
    k_scan<<<1, 1024, 0, stream>>>(counts, offsets);
    k_place<<<(N_PAIR + 255) / 256, 256, 0, stream>>>(idx_j, offsets, cnt2, sorted, rank);
    k_wc<<<48, 256, 0, stream>>>(WQ, WK, av, W2, b2, Wc, bc);
    k_gfused<<<dim3(N_ATOMS / 64, 48), 256, 0, stream>>>(x, Wc, bc, Gq, Gk, bq, bk);
    k_h1<<<N_PAIR / 64, 256, 0, stream>>>(rbf, W1, b1, h1);
    k_alphak<<<N_PAIR / 64, 256, 0, stream>>>(sorted, idx_j, h1, Gk, bk, alphaKs);
    k_alphaA<<<N_PAIR / 64, 256, 0, stream>>>(idx_i, rank, phi, mask, h1, Gq, bq,
                                              alphaKs, alphaF);
    k_aggr4<<<N_ATOMS / ATB, 256, 0, stream>>>(x, sph, mask, idx_i, idx_j, alphaF,
                                               row_start, out);
}

// Round 9
// 208.575 us; speedup vs baseline: 1.1198x; 1.1198x over previous
//
#include <hip/hip_runtime.h>
#include <hip/hip_bf16.h>

#define N_ATOMS 8192
#define N_PAIR  131072
#define F       128
#define N_HEAD  8
#define FH      16
#define N_DEG   3
#define M_TOT   15
#define K_RBF   32
#define H_FILT  64
#define FILT_OUT 768
#define NDH     24   // N_DEG * N_HEAD
#define ATB     4    // atoms per aggr block

typedef __attribute__((ext_vector_type(8))) unsigned short u16x8;

__device__ __forceinline__ float bf2f(unsigned short u) {
    return __uint_as_float(((unsigned)u) << 16);
}
__device__ __forceinline__ unsigned short f2bfbits(float f) {
    __hip_bfloat16 b = __float2bfloat16(f);
    return *reinterpret_cast<unsigned short*>(&b);
}

// ---------------- K0: segment starts (idx_i is sorted) ----------------
__global__ void k_seg(const int* __restrict__ idx_i, int* __restrict__ row_start) {
    int p = blockIdx.x * 256 + threadIdx.x;
    if (p >= N_PAIR) return;
    int ii = idx_i[p];
    int prev = (p == 0) ? -1 : idx_i[p - 1];
    for (int a = prev + 1; a <= ii; ++a) row_start[a] = p;
    if (p == N_PAIR - 1) {
        for (int a = ii + 1; a <= N_ATOMS; ++a) row_start[a] = N_PAIR;
    }
}

// ---------------- zero counters (graph-replay safe) ----------------
__global__ void k_zero(int* __restrict__ counts, int* __restrict__ cnt2) {
    int t = blockIdx.x * 256 + threadIdx.x;
    if (t < N_ATOMS) { counts[t] = 0; cnt2[t] = 0; }
}

// ---------------- histogram of idx_j ----------------
__global__ void k_hist(const int* __restrict__ idx_j, int* __restrict__ counts) {
    int p = blockIdx.x * 256 + threadIdx.x;
    if (p < N_PAIR) atomicAdd(&counts[idx_j[p]], 1);
}

// ---------------- exclusive scan of 8192 counts (1 block) ----------------
__global__ __launch_bounds__(1024) void k_scan(const int* __restrict__ counts,
                                               int* __restrict__ offsets) {
    __shared__ int ts[1024];
    int tid = threadIdx.x;
    int base = tid * 8;
    int v[8]; int tot = 0;
    #pragma unroll
    for (int q = 0; q < 8; ++q) { v[q] = counts[base + q]; tot += v[q]; }
    ts[tid] = tot; __syncthreads();
    for (int off = 1; off < 1024; off <<= 1) {
        int t2 = (tid >= off) ? ts[tid - off] : 0;
        __syncthreads();
        ts[tid] += t2;
        __syncthreads();
    }
    int excl = ts[tid] - tot;
    #pragma unroll
    for (int q = 0; q < 8; ++q) { offsets[base + q] = excl; excl += v[q]; }
    if (tid == 1023) offsets[N_ATOMS] = ts[1023];
}

// ---------------- placement: sorted pair ids per j-bucket + rank ----------------
__global__ void k_place(const int* __restrict__ idx_j, const int* __restrict__ offsets,
                        int* __restrict__ cnt2, int* __restrict__ sorted,
                        int* __restrict__ rank) {
    int p = blockIdx.x * 256 + threadIdx.x;
    if (p < N_PAIR) {
        int j = idx_j[p];
        int pos = offsets[j] + atomicAdd(&cnt2[j], 1);
        sorted[pos] = p;
        rank[p] = pos;
    }
}

// ---------------- K_wc: combined weights ----------------
__global__ __launch_bounds__(256) void k_wc(
    const float* __restrict__ WQ, const float* __restrict__ WK,
    const float* __restrict__ avec, const float* __restrict__ W2,
    const float* __restrict__ b2,
    float* __restrict__ Wc, float* __restrict__ bc)
{
    int bx = blockIdx.x;             // 0..47
    int side = bx / NDH, dh = bx % NDH;
    int d = dh >> 3, h = dh & 7;
    int colbase = d * 256 + h * 32 + side * 16;
    const float* W = (side == 0) ? WQ : WK;
    __shared__ float w2s[64][16];
    __shared__ float ws[16][16];     // W[d][h][c][j]
    __shared__ float as[16];
    __shared__ float b2s[16];
    int tid = threadIdx.x;
    for (int e = tid; e < 64 * 16; e += 256)
        w2s[e >> 4][e & 15] = W2[(e >> 4) * FILT_OUT + colbase + (e & 15)];
    if (tid < 16 * 16) ws[tid >> 4][tid & 15] = W[((d * 8 + h) * 16) * 16 + tid];
    if (tid < 16) { as[tid] = avec[dh * 32 + side * 16 + tid]; b2s[tid] = b2[colbase + tid]; }
    __syncthreads();
    for (int o = tid; o < 64 * 16; o += 256) {
        int k = o >> 4, j = o & 15;
        float s = 0.f;
        #pragma unroll
        for (int c = 0; c < 16; ++c) s += w2s[k][c] * as[c] * ws[c][j];
        Wc[((size_t)bx * 64 + k) * 16 + j] = s;
    }
    if (tid < 16) {
        float s = 0.f;
        #pragma unroll
        for (int c = 0; c < 16; ++c) s += b2s[c] * as[c] * ws[c][tid];
        bc[bx * 16 + tid] = s;
    }
}

// ---------------- K_gfused: x -> Gq/Gk/bq/bk directly ----------------
__global__ __launch_bounds__(256) void k_gfused(
    const float* __restrict__ x, const float* __restrict__ Wc,
    const float* __restrict__ bc,
    __hip_bfloat16* __restrict__ Gq, __hip_bfloat16* __restrict__ Gk,
    float* __restrict__ bq, float* __restrict__ bk)
{
    int bx = blockIdx.x;             // 128 blocks of 64 atoms
    int by = blockIdx.y;             // 0..47: side, dh
    int side = by / NDH, dh = by % NDH;
    int h = dh & 7;
    int n0 = bx * 64;
    __shared__ float xh[64][17];     // padded: conflict-free per-at reads
    __shared__ float bcs[16];
    int tid = threadIdx.x;
    for (int e = tid; e < 64 * 16; e += 256)
        xh[e >> 4][e & 15] = x[(size_t)(n0 + (e >> 4)) * F + h * 16 + (e & 15)];
    if (tid < 16) bcs[tid] = bc[by * 16 + tid];
    int k = tid & 63, wv = tid >> 6;
    float wcr[16];
    const float* wp = Wc + ((size_t)by * 64 + k) * 16;
    #pragma unroll
    for (int j = 0; j < 16; ++j) wcr[j] = wp[j];
    __syncthreads();
    __hip_bfloat16* G = (side == 0) ? Gq : Gk;
    #pragma unroll 4
    for (int it = 0; it < 16; ++it) {
        int at = wv * 16 + it;
        float acc = 0.f;
        #pragma unroll
        for (int j = 0; j < 16; ++j) acc += wcr[j] * xh[at][j];  // broadcast reads
        G[(size_t)(n0 + at) * 1536 + dh * 64 + k] = __float2bfloat16(acc);
    }
    if (tid < 64) {
        float* B = (side == 0) ? bq : bk;
        float s = 0.f;
        #pragma unroll
        for (int j = 0; j < 16; ++j) s += bcs[j] * xh[tid][j];
        B[(n0 + tid) * NDH + dh] = s;
    }
}

// ---------------- K2a: h1[p,64] = silu(rbf @ W1 + b1), bf16 ----------------
__global__ __launch_bounds__(256) void k_h1(
    const float* __restrict__ rbf, const float* __restrict__ W1,
    const float* __restrict__ b1, unsigned short* __restrict__ h1)
{
    __shared__ float w1s[K_RBF][H_FILT]; // 8 KB
    __shared__ float b1s[H_FILT];
    __shared__ float rbfs[64][33];       // padded
    int tid = threadIdx.x;
    int p0 = blockIdx.x * 64;
    for (int e = tid; e < K_RBF * H_FILT; e += 256) w1s[e >> 6][e & 63] = W1[e];
    if (tid < H_FILT) b1s[tid] = b1[tid];
    for (int e = tid; e < 64 * K_RBF; e += 256)
        rbfs[e >> 5][e & 31] = rbf[(size_t)p0 * K_RBF + e];
    __syncthreads();
    int pp = tid >> 2;
    int kbase = (tid & 3) * 16;
    float acc[16];
    #pragma unroll
    for (int q = 0; q < 16; ++q) acc[q] = b1s[kbase + q];
    for (int c = 0; c < K_RBF; ++c) {
        float r = rbfs[pp][c];
        #pragma unroll
        for (int q = 0; q < 16; ++q) acc[q] += r * w1s[c][kbase + q];
    }
    u16x8 o0, o1;
    #pragma unroll
    for (int q = 0; q < 8; ++q) {
        float s0 = acc[q];     o0[q] = f2bfbits(s0 / (1.f + __expf(-s0)));
        float s1 = acc[q + 8]; o1[q] = f2bfbits(s1 / (1.f + __expf(-s1)));
    }
    unsigned short* hp = h1 + (size_t)(p0 + pp) * 64 + kbase;
    *reinterpret_cast<u16x8*>(hp) = o0;
    *reinterpret_cast<u16x8*>(hp + 8) = o1;
}

// ---------------- K2c: K-side alpha, seg-parallel coalesced ----------------
// 8 lanes cooperate on one (slot,dh) row; lane reads contiguous 16B of Gk row.
__global__ __launch_bounds__(256) void k_alphak2(
    const int* __restrict__ sorted, const int* __restrict__ idx_j,
    const unsigned short* __restrict__ h1,
    const __hip_bfloat16* __restrict__ Gk, const float* __restrict__ bk,
    unsigned short* __restrict__ alphaKs)
{
    __shared__ unsigned short h1s[64][64]; // 8 KB
    __shared__ float als[64][24];          // 6 KB
    __shared__ int ps[64];
    __shared__ int js[64];
    int tid = threadIdx.x;
    int c0 = blockIdx.x * 64;
    if (tid < 64) {
        int pid = sorted[c0 + tid];
        ps[tid] = pid;
        js[tid] = idx_j[pid];
    }
    __syncthreads();
    for (int e = tid; e < 64 * 8; e += 256) {
        int slot = e >> 3, seg = e & 7;
        *reinterpret_cast<u16x8*>(&h1s[slot][seg * 8]) =
            *reinterpret_cast<const u16x8*>(h1 + (size_t)ps[slot] * 64 + seg * 8);
    }
    __syncthreads();
    const unsigned short* GkU = reinterpret_cast<const unsigned short*>(Gk);
    int seg = tid & 7;
    #pragma unroll 4
    for (int t = 0; t < 48; ++t) {
        int task = t * 256 + tid;          // 0..12287
        int dhslot = task >> 3;
        int slot = dhslot / 24;
        int dh = dhslot - slot * 24;
        const unsigned short* g = GkU + (size_t)js[slot] * 1536 + dh * 64 + seg * 8;
        u16x8 gv = *reinterpret_cast<const u16x8*>(g);
        u16x8 hv = *reinterpret_cast<const u16x8*>(&h1s[slot][seg * 8]);
        float p = 0.f;
        #pragma unroll
        for (int v = 0; v < 8; ++v) p += bf2f(gv[v]) * bf2f(hv[v]);
        p += __shfl_xor(p, 1);
        p += __shfl_xor(p, 2);
        p += __shfl_xor(p, 4);
        if (seg == 0) als[slot][dh] = p;
    }
    __syncthreads();
    // coalesced writeout + bk add
    for (int e = tid; e < 64 * 24; e += 256) {
        int slot = e / 24, dh = e - slot * 24;
        float val = als[slot][dh] + bk[js[slot] * NDH + dh];
        alphaKs[(size_t)c0 * 24 + e] = f2bfbits(val);
    }
}

// ---------------- K2d: full alpha in p-order, seg-parallel coalesced ----------------
__global__ __launch_bounds__(256) void k_alphaA2(
    const int* __restrict__ idx_i, const int* __restrict__ rank,
    const float* __restrict__ phi, const float* __restrict__ mask,
    const unsigned short* __restrict__ h1,
    const __hip_bfloat16* __restrict__ Gq, const float* __restrict__ bq,
    const unsigned short* __restrict__ alphaKs,
    float* __restrict__ alphaF)
{
    __shared__ unsigned short h1s[64][64]; // 8 KB
    __shared__ float als[64][24];          // 6 KB
    __shared__ int is[64];
    __shared__ int rks[64];
    __shared__ float pms[64];
    int tid = threadIdx.x;
    int p0 = blockIdx.x * 64;
    if (tid < 64) {
        int p = p0 + tid;
        is[tid] = idx_i[p];
        rks[tid] = rank[p];
        pms[tid] = phi[p] * mask[p] * 0.25f;
    }
    __syncthreads();
    for (int e = tid; e < 64 * 8; e += 256) {
        int slot = e >> 3, seg = e & 7;
        *reinterpret_cast<u16x8*>(&h1s[slot][seg * 8]) =
            *reinterpret_cast<const u16x8*>(h1 + (size_t)(p0 + slot) * 64 + seg * 8);
    }
    __syncthreads();
    const unsigned short* GqU = reinterpret_cast<const unsigned short*>(Gq);
    int seg = tid & 7;
    #pragma unroll 4
    for (int t = 0; t < 48; ++t) {
        int task = t * 256 + tid;
        int dhslot = task >> 3;
        int slot = dhslot / 24;
        int dh = dhslot - slot * 24;
        const unsigned short* g = GqU + (size_t)is[slot] * 1536 + dh * 64 + seg * 8;
        u16x8 gv = *reinterpret_cast<const u16x8*>(g);
        u16x8 hv = *reinterpret_cast<const u16x8*>(&h1s[slot][seg * 8]);
        float p = 0.f;
        #pragma unroll
        for (int v = 0; v < 8; ++v) p += bf2f(gv[v]) * bf2f(hv[v]);
        p += __shfl_xor(p, 1);
        p += __shfl_xor(p, 2);
        p += __shfl_xor(p, 4);
        if (seg == 0) als[slot][dh] = p;
    }
    __syncthreads();
    // coalesced writeout: + bq + alphaKs[rank] then * phi*mask/4
    for (int e = tid; e < 64 * 24; e += 256) {
        int slot = e / 24, dh = e - slot * 24;
        float val = als[slot][dh] + bq[is[slot] * NDH + dh]
                  + bf2f(alphaKs[(size_t)rks[slot] * 24 + dh]);
        alphaF[(size_t)p0 * 24 + e] = val * pms[slot];
    }
}

// ---------------- K3: multi-atom segment-sum with register accumulators ----------------
__global__ __launch_bounds__(256) void k_aggr4(
    const float* __restrict__ x, const float* __restrict__ sph,
    const float* __restrict__ mask,
    const int* __restrict__ idx_i, const int* __restrict__ idx_j,
    const float* __restrict__ alphaF,
    const int* __restrict__ row_start, float* __restrict__ out)
{
    int a0 = blockIdx.x * ATB;
    int tid = threadIdx.x;
    int f = tid & 127, grp = tid >> 7, h = f >> 4;

    __shared__ float xls[32][128];   // 16 KB (x rows * mask)
    __shared__ float als[32][24];    // 3 KB
    __shared__ float sls[32][15];    // 1.9 KB
    __shared__ int   iis[32];
    __shared__ int   jjs[32];
    __shared__ float xms[32];
    __shared__ int   rs[ATB + 1];

    if (tid <= ATB) rs[tid] = row_start[a0 + tid];
    __syncthreads();
    int pstart = rs[0], pend = rs[ATB];

    float acc[8];
    #pragma unroll
    for (int m = 0; m < 8; ++m) acc[m] = 0.f;
    int cur = -1;

    for (int pc = pstart; pc < pend; pc += 32) {
        int nb = min(32, pend - pc);
        __syncthreads();
        if (tid < nb) {
            int p = pc + tid;
            iis[tid] = idx_i[p];
            jjs[tid] = idx_j[p];
            xms[tid] = mask[p];
        }
        for (int e = tid; e < nb * 24; e += 256)
            als[e / 24][e % 24] = alphaF[(size_t)pc * 24 + e];
        for (int e = tid; e < nb * 15; e += 256)
            sls[e / 15][e % 15] = sph[(size_t)pc * 15 + e];
        __syncthreads();
        for (int e = tid; e < nb * 32; e += 256) {
            int q = e >> 5, c4 = e & 31;
            float4 v = *reinterpret_cast<const float4*>(x + (size_t)jjs[q] * F + c4 * 4);
            float m_ = xms[q];
            v.x *= m_; v.y *= m_; v.z *= m_; v.w *= m_;
            *reinterpret_cast<float4*>(&xls[q][c4 * 4]) = v;
        }
        __syncthreads();
        for (int q = 0; q < nb; ++q) {
            int ia = iis[q];
            if (ia != cur) {                 // uniform across block
                if (cur >= 0) {
                    size_t ob = (size_t)cur * (M_TOT * F) + f;
                    if (grp == 0) {
                        #pragma unroll
                        for (int m = 0; m < 8; ++m) out[ob + m * 128] = acc[m];
                    } else {
                        #pragma unroll
                        for (int m = 0; m < 7; ++m) out[ob + (8 + m) * 128] = acc[m];
                    }
                }
                cur = ia;
                #pragma unroll
                for (int m = 0; m < 8; ++m) acc[m] = 0.f;
            }
            float xv = xls[q][f];
            if (grp == 0) {
                float t0 = als[q][h] * xv;
                float t1 = als[q][8 + h] * xv;
                acc[0] += t0 * sls[q][0];
                acc[1] += t0 * sls[q][1];
                acc[2] += t0 * sls[q][2];
                #pragma unroll
                for (int m = 3; m < 8; ++m) acc[m] += t1 * sls[q][m];
            } else {
                float t2 = als[q][16 + h] * xv;
                #pragma unroll
                for (int m = 0; m < 7; ++m) acc[m] += t2 * sls[q][8 + m];
            }
        }
    }
    if (cur >= 0) {
        size_t ob = (size_t)cur * (M_TOT * F) + f;
        if (grp == 0) {
            #pragma unroll
            for (int m = 0; m < 8; ++m) out[ob + m * 128] = acc[m];
        } else {
            #pragma unroll
            for (int m = 0; m < 7; ++m) out[ob + (8 + m) * 128] = acc[m];
        }
    }
    // zero-fill atoms with no pairs
    for (int a = 0; a < ATB; ++a) {
        if (rs[a] == rs[a + 1]) {
            size_t ob = (size_t)(a0 + a) * (M_TOT * F) + f;
            if (grp == 0) {
                #pragma unroll
                for (int m = 0; m < 8; ++m) out[ob + m * 128] = 0.f;
            } else {
                #pragma unroll
                for (int m = 0; m < 7; ++m) out[ob + (8 + m) * 128] = 0.f;
            }
        }
    }
}

extern "C" void kernel_launch(void* const* d_in, const int* in_sizes, int n_in,
                              void* d_out, int out_size, void* d_ws, size_t ws_size,
                              hipStream_t stream) {
    const float* x     = (const float*)d_in[0];
    const float* rbf   = (const float*)d_in[1];
    const float* sph   = (const float*)d_in[2];
    const float* phi   = (const float*)d_in[3];
    const int*   idx_i = (const int*)d_in[4];
    const int*   idx_j = (const int*)d_in[5];
    const float* mask  = (const float*)d_in[6];
    const float* WQ    = (const float*)d_in[7];
    const float* WK    = (const float*)d_in[8];
    const float* av    = (const float*)d_in[9];
    const float* W1    = (const float*)d_in[10];
    const float* b1    = (const float*)d_in[11];
    const float* W2    = (const float*)d_in[12];
    const float* b2    = (const float*)d_in[13];
    float* out = (float*)d_out;
    char* ws = (char*)d_ws;

    // ws layout (bytes):
    // Gq   bf16 [0,        25165824)
    // Gk   bf16 [25165824, 50331648)  -- dead after k_alphak2; alphaF f32 aliases it
    // bq   f32  [50331648, 51118080)
    // bk   f32  [51118080, 51904512)
    // row_start [51904512, 51937792)   (8193 ints, padded)
    // counts    [51937792, 51970560)
    // offsets   [51970560, 52003840)   (8193 ints, padded)
    // cnt2      [52003840, 52036608)
    // sorted    [52036608, 52560896)
    // rank      [52560896, 53085184)
    // h1   bf16 [53085184, 69862400)
    // alphaKs bf16 [69862400, 76153856)
    // Wc   f32  [76153856, 76350464)
    // bc   f32  [76350464, 76356608)
    __hip_bfloat16* Gq = (__hip_bfloat16*)(ws + 0);
    __hip_bfloat16* Gk = (__hip_bfloat16*)(ws + 25165824);
    float* alphaF = (float*)(ws + 25165824);       // aliases Gk (dead after k_alphak2)
    float* bq = (float*)(ws + 50331648);
    float* bk = (float*)(ws + 51118080);
    int* row_start = (int*)(ws + 51904512);
    int* counts    = (int*)(ws + 51937792);
    int* offsets   = (int*)(ws + 51970560);
    int* cnt2      = (int*)(ws + 52003840);
    int* sorted    = (int*)(ws + 52036608);
    int* rank      = (int*)(ws + 52560896);
    unsigned short* h1      = (unsigned short*)(ws + 53085184);
    unsigned short* alphaKs = (unsigned short*)(ws + 69862400);
    float* Wc = (float*)(ws + 76153856);
    float* bc = (float*)(ws + 76350464);

    k_zero<<<(N_ATOMS + 255) / 256, 256, 0, stream>>>(counts, cnt2);
    k_seg<<<(N_PAIR + 255) / 256, 256, 0, stream>>>(idx_i, row_start);
    k_hist<<<(N_PAIR + 255) / 256, 256, 0, stream>>>(idx_j, counts);
    k_scan<<<1, 1024, 0, stream>>>(counts, offsets);
    k_place<<<(N_PAIR + 255) / 256, 256, 0, stream>>>(idx_j, offsets, cnt2, sorted, rank);
    k_wc<<<48, 256, 0, stream>>>(WQ, WK, av, W2, b2, Wc, bc);
    k_gfused<<<dim3(N_ATOMS / 64, 48), 256, 0, stream>>>(x, Wc, bc, Gq, Gk, bq, bk);
    k_h1<<<N_PAIR / 64, 256, 0, stream>>>(rbf, W1, b1, h1);
    k_alphak2<<<N_PAIR / 64, 256, 0, stream>>>(sorted, idx_j, h1, Gk, bk, alphaKs);
    k_alphaA2<<<N_PAIR / 64, 256, 0, stream>>>(idx_i, rank, phi, mask, h1, Gq, bq,
                                               alphaKs, alphaF);
    k_aggr4<<<N_ATOMS / ATB, 256, 0, stream>>>(x, sph, mask, idx_i, idx_j, alphaF,
                                               row_start, out);
}